// Round 4
// baseline (570.500 us; speedup 1.0000x reference)
//
#include <hip/hip_runtime.h>
#include <hip/hip_cooperative_groups.h>

namespace cg = cooperative_groups;

// B=4, N=128, L=20, D=512
#define Bc 4
#define Nc 128
#define Lc 20
#define Dc 512
#define SCALE 0.04419417382415922f   // 1/sqrt(512)
#define NL2E -1.4426950408889634f    // -log2(e)

#if __has_builtin(__builtin_amdgcn_exp2f)
#define EXP2(x) __builtin_amdgcn_exp2f(x)
#else
#define EXP2(x) __expf((x) * 0.6931471805599453f)
#endif

// One cooperative kernel, 512 blocks x 256 threads, grid.sync between phases.
// Phase A: q = f_b@Wq^T+bq (512 rows), k = f_w@Wk^T+bk (80 rows)  [32x32 reg-tiled]
// Phase B: cross-attn over L=20 + sentence gate -> f_bq
// Phase C: self-attn softmax rows -> A_b, A_bT
// Phase D: gated moment reduction + f_bb + residual -> out
__global__ __launch_bounds__(256, 2)
void mega(const float* __restrict__ f_b, const float* __restrict__ f_w,
          const float* __restrict__ f_s, const float* __restrict__ f_m,
          const float* __restrict__ Wq, const float* __restrict__ bq,
          const float* __restrict__ Wk, const float* __restrict__ bk,
          float* __restrict__ qb, float* __restrict__ kb,
          float* __restrict__ f_bq, float* __restrict__ A_b,
          float* __restrict__ A_bT, float* __restrict__ out)
{
    cg::grid_group grid = cg::this_grid();
    const int blk  = blockIdx.x;     // 0..511
    const int t    = threadIdx.x;    // 0..255
    const int lane = t & 63, wave = t >> 6;

    __shared__ __align__(16) float sm[1088];   // 4.4 KB, reused per phase

    // ---------------- Phase A: projections (32x32 tiles, 2x2 micro) ------
    if (blk < 304) {
        const int tr = blk >> 4, tc = blk & 15;
        const int c0 = tc * 32;
        const bool isq = tr < 16;
        const float* Ain  = isq ? f_b : f_w;
        const float* W    = isq ? Wq : Wk;
        const float* bias = isq ? bq : bk;
        float* C          = isq ? qb : kb;
        const int r0    = isq ? tr * 32 : (tr - 16) * 32;
        const int nrows = isq ? 512 : 80;

        float* As = sm;            // [16][34] transposed (k-major), pad->b64 align
        float* Bs = sm + 544;      // [16][34]

        const int sr   = t >> 3;            // 0..31 staged row
        const int sk2  = (t & 7) * 2;       // 0..14 staged k pair
        const int arow = min(r0 + sr, nrows - 1);
        const int wrow = c0 + sr;

        const int ty2 = (t >> 4) * 2;       // output rows (pair)
        const int tx2 = (t & 15) * 2;       // output cols (pair)
        float a00 = 0.f, a01 = 0.f, a10 = 0.f, a11 = 0.f;

        for (int k0 = 0; k0 < Dc; k0 += 16) {
            const float2 ga = *(const float2*)&Ain[arow * Dc + k0 + sk2];
            const float2 gb = *(const float2*)&W[wrow * Dc + k0 + sk2];
            __syncthreads();
            As[sk2 * 34 + sr]       = ga.x;
            As[(sk2 + 1) * 34 + sr] = ga.y;
            Bs[sk2 * 34 + sr]       = gb.x;
            Bs[(sk2 + 1) * 34 + sr] = gb.y;
            __syncthreads();
#pragma unroll
            for (int kk = 0; kk < 16; kk++) {
                const float2 av = *(const float2*)&As[kk * 34 + ty2];   // 16-lane bcast
                const float2 bv = *(const float2*)&Bs[kk * 34 + tx2];   // conflict-free
                a00 += av.x * bv.x; a01 += av.x * bv.y;
                a10 += av.y * bv.x; a11 += av.y * bv.y;
            }
        }
        const int orow = r0 + ty2;
        const float b0 = bias[c0 + tx2], b1 = bias[c0 + tx2 + 1];
        if (orow < nrows)
            *(float2*)&C[orow * Dc + c0 + tx2] = make_float2(a00 + b0, a01 + b1);
        if (orow + 1 < nrows)
            *(float2*)&C[(orow + 1) * Dc + c0 + tx2] = make_float2(a10 + b0, a11 + b1);
    }

    __threadfence();
    grid.sync();

    // ---------------- Phase B: cross-attn + gate -> f_bq ------------------
    {
        const int bn = blk, b = bn >> 7;
        float* qs = sm;            // 512
        float* sc = sm + 512;      // 32

        qs[t]       = qb[bn * Dc + t];
        qs[t + 256] = qb[bn * Dc + t + 256];
        __syncthreads();

        for (int l = wave; l < Lc; l += 4) {
            const float* kr = kb + (b * Lc + l) * Dc;
            float s = 0.f;
#pragma unroll
            for (int off = 0; off < Dc; off += 64) s += qs[lane + off] * kr[lane + off];
#pragma unroll
            for (int d = 32; d >= 1; d >>= 1) s += __shfl_down(s, d, 64);
            if (lane == 0) sc[l] = s * SCALE;
        }
        __syncthreads();

        if (t == 0) {
            float mx = sc[0];
            for (int l = 1; l < Lc; l++) mx = fmaxf(mx, sc[l]);
            float sum = 0.f;
            for (int l = 0; l < Lc; l++) { float e = __expf(sc[l] - mx); sc[l] = e; sum += e; }
            sm[544] = 1.0f / sum;
        }
        __syncthreads();
        const float inv = sm[544];

#pragma unroll
        for (int half = 0; half < 2; half++) {
            const int d = t + half * 256;
            float acc = 0.f;
#pragma unroll 4
            for (int l = 0; l < Lc; l++) acc += sc[l] * f_w[(b * Lc + l) * Dc + d];
            acc = acc * inv + f_s[b * Dc + d];
            f_bq[bn * Dc + d] = f_b[bn * Dc + d] * acc;
        }
    }

    __threadfence();
    grid.sync();

    // ---------------- Phase C: self-attn softmax -> A_b, A_bT -------------
    {
        const int bn = blk, b = bn >> 7, n = bn & 127;
        float* qrow = sm;          // 512
        float* sc   = sm + 512;    // 128
        float* red  = sm + 640;    // 128

        qrow[t]       = f_bq[bn * Dc + t];
        qrow[t + 256] = f_bq[bn * Dc + 256 + t];
        __syncthreads();

        const float4* q4 = (const float4*)qrow;
        const float4 qa = q4[lane];
        const float4 qv = q4[lane + 64];

        for (int m = wave; m < Nc; m += 4) {
            const float4* kr = (const float4*)(f_bq + (b * Nc + m) * Dc);
            const float4 va = kr[lane];
            const float4 vb = kr[lane + 64];
            float s = qa.x * va.x + qa.y * va.y + qa.z * va.z + qa.w * va.w
                    + qv.x * vb.x + qv.y * vb.y + qv.z * vb.z + qv.w * vb.w;
#pragma unroll
            for (int d = 32; d >= 1; d >>= 1) s += __shfl_down(s, d, 64);
            if (lane == 0) sc[m] = s * SCALE;
        }
        __syncthreads();

        float e = 0.f, sval = 0.f;
        if (t < Nc) { sval = sc[t]; red[t] = sval; }
        __syncthreads();
        for (int st = 64; st >= 1; st >>= 1) {
            if (t < st) red[t] = fmaxf(red[t], red[t + st]);
            __syncthreads();
        }
        const float mx = red[0];
        __syncthreads();
        if (t < Nc) { e = __expf(sval - mx); red[t] = e; }
        __syncthreads();
        for (int st = 64; st >= 1; st >>= 1) {
            if (t < st) red[t] += red[t + st];
            __syncthreads();
        }
        if (t < Nc) {
            const float a = e * (1.0f / red[0]);
            A_b[bn * Nc + t] = a;
            A_bT[(b * Nc + t) * Nc + n] = a;
        }
    }

    __threadfence();
    grid.sync();

    // ---------------- Phase D: moment + f_bb + residual -> out ------------
    {
        const int bj = blk, b = bj >> 7, j = bj & 127;
        const int c = t & 127, half = t >> 7;
        float* w    = sm;                    // 128
        float* ar   = sm + 128;              // 128
        float4* pex = (float4*)(sm + 256);   // 128 float4

        if (t < Nc) w[t] = A_bT[bj * Nc + t];
        else        ar[t - Nc] = A_b[bj * Nc + (t - Nc)];
        __syncthreads();

        const float4 s4 = ((const float4*)(f_s + b * Dc))[c];
        const float4 ns = make_float4(NL2E * s4.x, NL2E * s4.y, NL2E * s4.z, NL2E * s4.w);

        float4 acc = make_float4(0.f, 0.f, 0.f, 0.f);
        const float4* fm4 = (const float4*)f_m;
        int idx = ((b * Nc + half * 64) * Nc + j) * (Dc / 4) + c;

#pragma unroll 8
        for (int i = 0; i < 64; i++) {
            const float4 m4 = fm4[idx];
            idx += Nc * (Dc / 4);
            const float ww = w[half * 64 + i];
            acc.x += ww * m4.x * __builtin_amdgcn_rcpf(1.f + EXP2(m4.x * ns.x));
            acc.y += ww * m4.y * __builtin_amdgcn_rcpf(1.f + EXP2(m4.y * ns.y));
            acc.z += ww * m4.z * __builtin_amdgcn_rcpf(1.f + EXP2(m4.z * ns.z));
            acc.w += ww * m4.w * __builtin_amdgcn_rcpf(1.f + EXP2(m4.w * ns.w));
        }

        const float4* fb4 = (const float4*)(f_b + b * Nc * Dc);
#pragma unroll 4
        for (int m = half * 64; m < half * 64 + 64; m++) {
            const float a = ar[m];
            const float4 v = fb4[m * (Dc / 4) + c];
            acc.x += a * v.x; acc.y += a * v.y; acc.z += a * v.z; acc.w += a * v.w;
        }

        if (half == 1) pex[c] = acc;
        __syncthreads();
        if (half == 0) {
            const float4 p = pex[c];
            const float4 r = fb4[j * (Dc / 4) + c];
            acc.x += p.x + r.x; acc.y += p.y + r.y;
            acc.z += p.z + r.z; acc.w += p.w + r.w;
            ((float4*)out)[bj * (Dc / 4) + c] = acc;
        }
    }
}

// ---------------------------------------------------------------------------
extern "C" void kernel_launch(void* const* d_in, const int* in_sizes, int n_in,
                              void* d_out, int out_size, void* d_ws, size_t ws_size,
                              hipStream_t stream) {
    const float* f_b = (const float*)d_in[0];
    const float* f_w = (const float*)d_in[1];
    const float* f_s = (const float*)d_in[2];
    const float* f_m = (const float*)d_in[3];
    const float* Wq  = (const float*)d_in[4];
    const float* bq  = (const float*)d_in[5];
    const float* Wk  = (const float*)d_in[6];
    const float* bk  = (const float*)d_in[7];
    float* outp = (float*)d_out;

    float* ws   = (float*)d_ws;
    float* qb   = ws;                  // 512*512
    float* kb   = qb   + 512 * Dc;     // 80*512
    float* f_bq = kb   + 80 * Dc;      // 512*512
    float* A_b  = f_bq + 512 * Dc;     // 512*128
    float* A_bT = A_b  + 512 * Nc;     // 512*128

    void* args[] = {(void*)&f_b, (void*)&f_w, (void*)&f_s, (void*)&f_m,
                    (void*)&Wq,  (void*)&bq,  (void*)&Wk,  (void*)&bk,
                    (void*)&qb,  (void*)&kb,  (void*)&f_bq, (void*)&A_b,
                    (void*)&A_bT, (void*)&outp};
    hipLaunchCooperativeKernel((void*)mega, dim3(512), dim3(256), args, 0, stream);
}

// Round 5
// 263.605 us; speedup vs baseline: 2.1642x; 2.1642x over previous
//
#include <hip/hip_runtime.h>
#include <hip/hip_bf16.h>

// B=4, N=128, L=20, D=512
#define Bc 4
#define Nc 128
#define Lc 20
#define Dc 512
#define SCALE 0.04419417382415922f   // 1/sqrt(512)
#define NL2E -1.4426950408889634f    // -log2(e)

#if __has_builtin(__builtin_amdgcn_exp2f)
#define EXP2(x) __builtin_amdgcn_exp2f(x)
#else
#define EXP2(x) __expf((x) * 0.6931471805599453f)
#endif

// ---------------------------------------------------------------------------
// Kernel 1: q/k projections, 32x32 tiles, 2x2 micro-tile, k-major LDS.
//   blockIdx.y 0..15  -> q rows (512), blockIdx.y 16..18 -> k rows (80)
// ---------------------------------------------------------------------------
__global__ __launch_bounds__(256)
void proj_gemm(const float* __restrict__ f_b, const float* __restrict__ f_w,
               const float* __restrict__ Wq, const float* __restrict__ bq,
               const float* __restrict__ Wk, const float* __restrict__ bk,
               float* __restrict__ qb, float* __restrict__ kb) {
    const int t  = threadIdx.x;
    const int tr = blockIdx.y, tc = blockIdx.x;
    const int c0 = tc * 32;
    const bool isq = tr < 16;
    const float* Ain  = isq ? f_b : f_w;
    const float* W    = isq ? Wq : Wk;
    const float* bias = isq ? bq : bk;
    float* C          = isq ? qb : kb;
    const int r0    = isq ? tr * 32 : (tr - 16) * 32;
    const int nrows = isq ? 512 : 80;

    __shared__ __align__(16) float As[16 * 34];   // [k][row+pad]
    __shared__ __align__(16) float Bs[16 * 34];

    const int sr  = t >> 3;           // staged row 0..31
    const int sk2 = (t & 7) * 2;      // staged k pair 0..14
    const int arow = min(r0 + sr, nrows - 1);
    const int wrow = c0 + sr;

    const int ty2 = (t >> 4) * 2;     // out row pair
    const int tx2 = (t & 15) * 2;     // out col pair
    float a00 = 0.f, a01 = 0.f, a10 = 0.f, a11 = 0.f;

    for (int k0 = 0; k0 < Dc; k0 += 16) {
        const float2 ga = *(const float2*)&Ain[arow * Dc + k0 + sk2];
        const float2 gb = *(const float2*)&W[wrow * Dc + k0 + sk2];
        __syncthreads();
        As[sk2 * 34 + sr]       = ga.x;
        As[(sk2 + 1) * 34 + sr] = ga.y;
        Bs[sk2 * 34 + sr]       = gb.x;
        Bs[(sk2 + 1) * 34 + sr] = gb.y;
        __syncthreads();
#pragma unroll
        for (int kk = 0; kk < 16; kk++) {
            const float2 av = *(const float2*)&As[kk * 34 + ty2];
            const float2 bv = *(const float2*)&Bs[kk * 34 + tx2];
            a00 = fmaf(av.x, bv.x, a00); a01 = fmaf(av.x, bv.y, a01);
            a10 = fmaf(av.y, bv.x, a10); a11 = fmaf(av.y, bv.y, a11);
        }
    }
    const int orow = r0 + ty2;
    const float b0 = bias[c0 + tx2], b1 = bias[c0 + tx2 + 1];
    if (orow < nrows)
        *(float2*)&C[orow * Dc + c0 + tx2] = make_float2(a00 + b0, a01 + b1);
    if (orow + 1 < nrows)
        *(float2*)&C[(orow + 1) * Dc + c0 + tx2] = make_float2(a10 + b0, a11 + b1);
}

// ---------------------------------------------------------------------------
// Kernel 2: cross-attention over L=20 + sentence gate -> f_bq  (vectorized)
// ---------------------------------------------------------------------------
__global__ __launch_bounds__(256)
void cross_attn_gate(const float* __restrict__ q,    // [B*N, D]
                     const float* __restrict__ k,    // [B*L, D]
                     const float* __restrict__ f_w,  // [B*L, D]
                     const float* __restrict__ f_b,  // [B*N, D]
                     const float* __restrict__ f_s,  // [B, D]
                     float* __restrict__ f_bq) {     // [B*N, D]
    const int bn = blockIdx.x;
    const int b  = bn >> 7;
    const int t  = threadIdx.x;          // 0..255
    const int lane = t & 63, wave = t >> 6;

    __shared__ __align__(16) float qs[Dc];
    __shared__ float sc[32];
    __shared__ float invs;

    ((float2*)qs)[t] = ((const float2*)(q + bn * Dc))[t];
    __syncthreads();

    const float4* q4 = (const float4*)qs;
    const float4 qa = q4[lane];
    const float4 qv = q4[lane + 64];

    for (int l = wave; l < Lc; l += 4) {
        const float4* kr = (const float4*)(k + (b * Lc + l) * Dc);
        const float4 ka = kr[lane];
        const float4 kv = kr[lane + 64];
        float s = qa.x * ka.x + qa.y * ka.y + qa.z * ka.z + qa.w * ka.w
                + qv.x * kv.x + qv.y * kv.y + qv.z * kv.z + qv.w * kv.w;
#pragma unroll
        for (int d = 32; d >= 1; d >>= 1) s += __shfl_down(s, d, 64);
        if (lane == 0) sc[l] = s * SCALE;
    }
    __syncthreads();

    if (t == 0) {
        float mx = sc[0];
        for (int l = 1; l < Lc; l++) mx = fmaxf(mx, sc[l]);
        float sum = 0.f;
        for (int l = 0; l < Lc; l++) { float e = __expf(sc[l] - mx); sc[l] = e; sum += e; }
        invs = 1.0f / sum;
    }
    __syncthreads();
    const float inv = invs;

    const float2* fw2 = (const float2*)(f_w + b * Lc * Dc);   // [L][256] float2
    float2 acc = make_float2(0.f, 0.f);
#pragma unroll 5
    for (int l = 0; l < Lc; l++) {
        const float2 v = fw2[l * 256 + t];
        const float w = sc[l];
        acc.x = fmaf(w, v.x, acc.x);
        acc.y = fmaf(w, v.y, acc.y);
    }
    const float2 s2 = ((const float2*)(f_s + b * Dc))[t];
    const float2 fb2 = ((const float2*)(f_b + bn * Dc))[t];
    float2 o;
    o.x = fb2.x * (acc.x * inv + s2.x);
    o.y = fb2.y * (acc.y * inv + s2.y);
    ((float2*)(f_bq + bn * Dc))[t] = o;
}

// ---------------------------------------------------------------------------
// Kernel 3: A_b[b,n,:] = softmax_m(f_bq[b,n]·f_bq[b,m] * scale)
// wave-per-m (coalesced), also writes A_bT.
// ---------------------------------------------------------------------------
__global__ __launch_bounds__(256)
void self_attn_scores(const float* __restrict__ f_bq,  // [B*N, D]
                      float* __restrict__ A_b,         // [B*N, N]
                      float* __restrict__ A_bT) {      // [B*N, N]
    const int bn = blockIdx.x;
    const int b  = bn >> 7, n = bn & 127;
    const int t  = threadIdx.x;          // 0..255
    const int lane = t & 63, wave = t >> 6;

    __shared__ __align__(16) float qrow[Dc];
    __shared__ float sc[Nc];
    __shared__ float red[Nc];

    qrow[t]       = f_bq[bn * Dc + t];
    qrow[t + 256] = f_bq[bn * Dc + 256 + t];
    __syncthreads();

    const float4* q4 = (const float4*)qrow;
    const float4 qa = q4[lane];
    const float4 qv = q4[lane + 64];

    for (int m = wave; m < Nc; m += 4) {
        const float4* kr = (const float4*)(f_bq + (b * Nc + m) * Dc);
        const float4 va = kr[lane];
        const float4 vb = kr[lane + 64];
        float s = qa.x * va.x + qa.y * va.y + qa.z * va.z + qa.w * va.w
                + qv.x * vb.x + qv.y * vb.y + qv.z * vb.z + qv.w * vb.w;
#pragma unroll
        for (int d = 32; d >= 1; d >>= 1) s += __shfl_down(s, d, 64);
        if (lane == 0) sc[m] = s * SCALE;
    }
    __syncthreads();

    float e = 0.f, sval = 0.f;
    if (t < Nc) { sval = sc[t]; red[t] = sval; }
    __syncthreads();
    for (int st = 64; st >= 1; st >>= 1) {
        if (t < st) red[t] = fmaxf(red[t], red[t + st]);
        __syncthreads();
    }
    const float mx = red[0];
    __syncthreads();
    if (t < Nc) { e = __expf(sval - mx); red[t] = e; }
    __syncthreads();
    for (int st = 64; st >= 1; st >>= 1) {
        if (t < st) red[t] += red[t + st];
        __syncthreads();
    }
    if (t < Nc) {
        const float a = e * (1.0f / red[0]);
        A_b[bn * Nc + t] = a;
        A_bT[(b * Nc + t) * Nc + n] = a;
    }
}

// ---------------------------------------------------------------------------
// Kernel 4: fused moment reduction + self-attn apply + residual.
// out[b,j,:] = f_b[b,j,:] + sum_m A_b[b,j,m] f_b[b,m,:]
//            + sum_i A_b[b,i,j] * sigmoid(f_m*f_s)*f_m
// one block per (b,j), 256 threads: c = float4 column, half = i-split.
// ---------------------------------------------------------------------------
__global__ __launch_bounds__(256)
void moment_final(const float* __restrict__ f_m,   // [B,N,N,D]
                  const float* __restrict__ f_s,   // [B,D]
                  const float* __restrict__ A_b,   // [B*N, N]
                  const float* __restrict__ A_bT,  // [B*N, N]
                  const float* __restrict__ f_b,   // [B*N, D]
                  float* __restrict__ out) {       // [B*N, D]
    const int bj = blockIdx.x;
    const int b  = bj >> 7, j = bj & 127;
    const int t  = threadIdx.x;        // 0..255
    const int c    = t & 127;
    const int half = t >> 7;

    __shared__ float w[Nc];
    __shared__ float ar[Nc];
    __shared__ __align__(16) float4 pex[Nc];

    if (t < Nc) w[t] = A_bT[bj * Nc + t];
    else        ar[t - Nc] = A_b[bj * Nc + (t - Nc)];
    __syncthreads();

    const float4 s4 = ((const float4*)(f_s + b * Dc))[c];
    const float4 ns = make_float4(NL2E * s4.x, NL2E * s4.y, NL2E * s4.z, NL2E * s4.w);

    float4 acc = make_float4(0.f, 0.f, 0.f, 0.f);
    const float4* fm4 = (const float4*)f_m;
    int idx = ((b * Nc + half * 64) * Nc + j) * (Dc / 4) + c;

#pragma unroll 16
    for (int i = 0; i < 64; i++) {
        const float4 m4 = fm4[idx];
        idx += Nc * (Dc / 4);
        const float ww = w[half * 64 + i];
        acc.x = fmaf(ww * m4.x, __builtin_amdgcn_rcpf(1.f + EXP2(m4.x * ns.x)), acc.x);
        acc.y = fmaf(ww * m4.y, __builtin_amdgcn_rcpf(1.f + EXP2(m4.y * ns.y)), acc.y);
        acc.z = fmaf(ww * m4.z, __builtin_amdgcn_rcpf(1.f + EXP2(m4.z * ns.z)), acc.z);
        acc.w = fmaf(ww * m4.w, __builtin_amdgcn_rcpf(1.f + EXP2(m4.w * ns.w)), acc.w);
    }

    const float4* fb4 = (const float4*)(f_b + b * Nc * Dc);
#pragma unroll 8
    for (int m = half * 64; m < half * 64 + 64; m++) {
        const float a = ar[m];
        const float4 v = fb4[m * (Dc / 4) + c];
        acc.x = fmaf(a, v.x, acc.x); acc.y = fmaf(a, v.y, acc.y);
        acc.z = fmaf(a, v.z, acc.z); acc.w = fmaf(a, v.w, acc.w);
    }

    if (half == 1) pex[c] = acc;
    __syncthreads();
    if (half == 0) {
        const float4 p = pex[c];
        const float4 r = fb4[j * (Dc / 4) + c];
        acc.x += p.x + r.x; acc.y += p.y + r.y;
        acc.z += p.z + r.z; acc.w += p.w + r.w;
        ((float4*)out)[bj * (Dc / 4) + c] = acc;
    }
}

// ---------------------------------------------------------------------------
extern "C" void kernel_launch(void* const* d_in, const int* in_sizes, int n_in,
                              void* d_out, int out_size, void* d_ws, size_t ws_size,
                              hipStream_t stream) {
    const float* f_b = (const float*)d_in[0];
    const float* f_w = (const float*)d_in[1];
    const float* f_s = (const float*)d_in[2];
    const float* f_m = (const float*)d_in[3];
    const float* Wq  = (const float*)d_in[4];
    const float* bq  = (const float*)d_in[5];
    const float* Wk  = (const float*)d_in[6];
    const float* bk  = (const float*)d_in[7];
    float* out = (float*)d_out;

    float* ws   = (float*)d_ws;
    float* qb   = ws;                  // 512*512
    float* kb   = qb   + 512 * Dc;     // 80*512
    float* f_bq = kb   + 80 * Dc;      // 512*512
    float* A_b  = f_bq + 512 * Dc;     // 512*128
    float* A_bT = A_b  + 512 * Nc;     // 512*128

    proj_gemm<<<dim3(16, 19), 256, 0, stream>>>(f_b, f_w, Wq, bq, Wk, bk, qb, kb);
    cross_attn_gate<<<Bc * Nc, 256, 0, stream>>>(qb, kb, f_w, f_b, f_s, f_bq);
    self_attn_scores<<<Bc * Nc, 256, 0, stream>>>(f_bq, A_b, A_bT);
    moment_final<<<Bc * Nc, 256, 0, stream>>>(f_m, f_s, A_b, A_bT, f_b, out);
}